// Round 9
// baseline (232.799 us; speedup 1.0000x reference)
//
#include <hip/hip_runtime.h>
#include <hip/hip_bf16.h>

// N=50000 nodes, F=64, H=2, E=800000.
// qk = x @ W_qk + b -> [N,H,2,F]; s[e,h] = <q[row],k[col]>; sparse softmax per row; mean heads.
// Softmax WITHOUT max subtraction (shift-invariant; |s| <~ 15, safe in fp32).
// R9: CSR row-grouping. Pipeline: gemm(MFMA) | memset | hist | scan(2-level) | scatter | row_k.
// row_k: one 16-lane group per row; q loaded once, den in-register (no global atomics for den),
// per-edge exp staged in L2-hot exb, output scattered by original edge id.
// R7 lesson: NO grid.sync on MI355X (cg barrier ~190us/sync @1024 blocks). Launches cost ~1-2us.
// MFMA 16x16x32 bf16 layouts (HW-verified): A[m=l&15][k=quad*8+j], B[k=quad*8+j][n=l&15],
// D col=l&15 row=quad*4+reg.

#define NFEAT 64
#define NCOL  256   // 2*H*F
#define WT_STRIDE 72  // shorts; 144B row stride: 16B-aligned

typedef __attribute__((ext_vector_type(8))) short bf16x8;
typedef __attribute__((ext_vector_type(4))) float f32x4;

__device__ __forceinline__ unsigned short f2bf(float f) {
    union { __hip_bfloat16 h; unsigned short u; } cv;
    cv.h = __float2bfloat16(f);
    return cv.u;
}

__device__ __forceinline__ float dot_bf16x2(unsigned a, unsigned b) {
    float alo = __uint_as_float(a << 16), ahi = __uint_as_float(a & 0xFFFF0000u);
    float blo = __uint_as_float(b << 16), bhi = __uint_as_float(b & 0xFFFF0000u);
    return alo * blo + ahi * bhi;
}

// ---------------- Kernel 1: qk projection via MFMA (W transpose folded in) ----------------
__global__ __launch_bounds__(256) void gemm_qk_mfma(
    const float* __restrict__ x, const float* __restrict__ W,
    const float* __restrict__ b,
    unsigned short* __restrict__ qo, unsigned short* __restrict__ ko, int N)
{
    __shared__ unsigned short WtL[NCOL * WT_STRIDE];  // 36.9 KB
    __shared__ float bL[NCOL];
    const int tid = threadIdx.x;

    for (int i = tid; i < NFEAT * NCOL; i += 256) {
        const int kk = i >> 8, c = i & 255;
        WtL[c * WT_STRIDE + kk] = f2bf(W[i]);
    }
    bL[tid] = b[tid];

    const int lane = tid & 63;
    const int wv   = tid >> 6;
    const int l15  = lane & 15;
    const int quad = lane >> 4;
    const int base = blockIdx.x * 128 + wv * 32;
    __syncthreads();

    if (base >= N) return;

    bf16x8 afrag[2][2];
#pragma unroll
    for (int s = 0; s < 2; ++s) {
        int m = base + s * 16 + l15;
        if (m >= N) m = N - 1;
        const float* xp = x + (size_t)m * NFEAT + quad * 8;
#pragma unroll
        for (int ks = 0; ks < 2; ++ks) {
            float4 a0 = *(const float4*)(xp + ks * 32);
            float4 a1 = *(const float4*)(xp + ks * 32 + 4);
            bf16x8 f;
            f[0] = f2bf(a0.x); f[1] = f2bf(a0.y); f[2] = f2bf(a0.z); f[3] = f2bf(a0.w);
            f[4] = f2bf(a1.x); f[5] = f2bf(a1.y); f[6] = f2bf(a1.z); f[7] = f2bf(a1.w);
            afrag[s][ks] = f;
        }
    }

#pragma unroll 4
    for (int ct = 0; ct < 16; ++ct) {
        const int c = ct * 16 + l15;
        bf16x8 b0 = *(const bf16x8*)(WtL + (size_t)c * WT_STRIDE + quad * 8);
        bf16x8 b1 = *(const bf16x8*)(WtL + (size_t)c * WT_STRIDE + 32 + quad * 8);
        const float bias = bL[c];
        const int h   = c >> 7;
        const int isk = (c >> 6) & 1;
        const int f0  = c & 63;
        unsigned short* dst = isk ? ko : qo;
#pragma unroll
        for (int s = 0; s < 2; ++s) {
            f32x4 acc = {0.f, 0.f, 0.f, 0.f};
            acc = __builtin_amdgcn_mfma_f32_16x16x32_bf16(afrag[s][0], b0, acc, 0, 0, 0);
            acc = __builtin_amdgcn_mfma_f32_16x16x32_bf16(afrag[s][1], b1, acc, 0, 0, 0);
#pragma unroll
            for (int r = 0; r < 4; ++r) {
                const int m = base + s * 16 + quad * 4 + r;
                if (m < N)
                    dst[(size_t)m * 128 + h * 64 + f0] = f2bf(acc[r] + bias);
            }
        }
    }
}

// ---------------- CSR build ----------------
__global__ __launch_bounds__(256) void hist_k(const int* __restrict__ ei,
                                              unsigned* __restrict__ cnt, int E) {
    const int e = blockIdx.x * 256 + threadIdx.x;
    if (e < E) atomicAdd(&cnt[ei[e]], 1u);
}

// exclusive scan of cnt[0..n-1] within 256-blocks; block totals to bsum
__global__ __launch_bounds__(256) void scan_a(const unsigned* __restrict__ cnt,
                                              unsigned* __restrict__ rsl,
                                              unsigned* __restrict__ bsum, int n) {
    __shared__ unsigned wsum[4];
    const int idx  = blockIdx.x * 256 + threadIdx.x;
    const int lane = threadIdx.x & 63;
    const int wv   = threadIdx.x >> 6;
    unsigned v = (idx < n) ? cnt[idx] : 0u;
    unsigned inc = v;
    for (int off = 1; off < 64; off <<= 1) {
        unsigned t = __shfl_up(inc, off, 64);
        if (lane >= off) inc += t;
    }
    if (lane == 63) wsum[wv] = inc;
    __syncthreads();
    unsigned wbase = 0;
    for (int i = 0; i < wv; ++i) wbase += wsum[i];
    if (idx < n) rsl[idx] = wbase + inc - v;
    if (threadIdx.x == 255) bsum[blockIdx.x] = wbase + inc;
}

// exclusive scan of bsum[0..nb-1] (nb <= 256), one block
__global__ __launch_bounds__(256) void scan_b(const unsigned* __restrict__ bsum,
                                              unsigned* __restrict__ bpre, int nb) {
    __shared__ unsigned wsum[4];
    const int t    = threadIdx.x;
    const int lane = t & 63;
    const int wv   = t >> 6;
    unsigned v = (t < nb) ? bsum[t] : 0u;
    unsigned inc = v;
    for (int off = 1; off < 64; off <<= 1) {
        unsigned u = __shfl_up(inc, off, 64);
        if (lane >= off) inc += u;
    }
    if (lane == 63) wsum[wv] = inc;
    __syncthreads();
    unsigned wbase = 0;
    for (int i = 0; i < wv; ++i) wbase += wsum[i];
    bpre[t] = wbase + inc - v;
}

__global__ __launch_bounds__(256) void scat_k(const int* __restrict__ ei,
                                              const unsigned* __restrict__ rsl,
                                              const unsigned* __restrict__ bpre,
                                              unsigned* __restrict__ cursor,
                                              uint2* __restrict__ csr, int E) {
    const int e = blockIdx.x * 256 + threadIdx.x;
    if (e >= E) return;
    const int r = ei[e];
    const unsigned base = rsl[r] + bpre[r >> 8];
    const unsigned p = base + atomicAdd(&cursor[r], 1u);
    csr[p] = make_uint2((unsigned)ei[E + e], (unsigned)e);   // {col, eid}
}

// ---------------- row kernel: per-row scores->exp->den->normalize ----------------
// 16 lanes per row. Pass1: gather k per edge, dot both heads, exp, stage to exb,
// accumulate den in-register. Barrier. Pass2: read back exb (L2-hot), scatter out[eid].
__global__ __launch_bounds__(256) void row_k(
    const unsigned short* __restrict__ q, const unsigned short* __restrict__ k,
    const uint2* __restrict__ csr, const unsigned* __restrict__ rsl,
    const unsigned* __restrict__ bpre, float* __restrict__ exb,
    float* __restrict__ out, int N)
{
    const int grp  = (int)((blockIdx.x * 256 + threadIdx.x) >> 4);
    const int lane = threadIdx.x & 15;
    const bool live = (grp < N);

    unsigned start = 0; int deg = 0;
    uint4 qa = make_uint4(0, 0, 0, 0);
    if (live) {
        start = rsl[grp] + bpre[grp >> 8];
        const unsigned end = rsl[grp + 1] + bpre[(grp + 1) >> 8];
        deg = (int)(end - start);
        qa = ((const uint4*)(q + (size_t)grp * 128))[lane];
    }

    float den0 = 0.f, den1 = 0.f;
    uint2 pr = (deg > 0) ? csr[start] : make_uint2(0u, 0u);
    for (int j = 0; j < deg; ++j) {
        uint2 nx = (j + 1 < deg) ? csr[start + j + 1] : pr;   // prefetch next
        uint4 ka = ((const uint4*)(k + (size_t)pr.x * 128))[lane];
        float p = dot_bf16x2(qa.x, ka.x) + dot_bf16x2(qa.y, ka.y)
                + dot_bf16x2(qa.z, ka.z) + dot_bf16x2(qa.w, ka.w);
        p += __shfl_xor(p, 1);
        p += __shfl_xor(p, 2);
        p += __shfl_xor(p, 4);
        if ((lane & 7) == 0) {
            const float e = __expf(p);
            exb[2 * (size_t)(start + j) + (lane >> 3)] = e;
            if (lane == 0) den0 += e; else den1 += e;
        }
        pr = nx;
    }

    __threadfence_block();
    __syncthreads();   // drains vmem: exb writes visible to all lanes of the block

    const float i0 = 1.f / __shfl(den0, 0, 16);
    const float i1 = 1.f / __shfl(den1, 8, 16);
    for (int j = lane; j < deg; j += 16) {
        const uint2 pe = csr[start + j];
        const float2 ev = ((const float2*)exb)[start + j];
        out[pe.y] = 0.5f * (ev.x * i0 + ev.y * i1);
    }
}

extern "C" void kernel_launch(void* const* d_in, const int* in_sizes, int n_in,
                              void* d_out, int out_size, void* d_ws, size_t ws_size,
                              hipStream_t stream)
{
    const float* x   = (const float*)d_in[0];
    const float* W   = (const float*)d_in[1];
    const float* b   = (const float*)d_in[2];
    const int*   ei  = (const int*)d_in[3];
    float*       out = (float*)d_out;

    const int N = in_sizes[0] / NFEAT;     // 50000
    const int E = in_sizes[3] / 2;         // 800000
    const int NB = (N + 1 + 255) / 256;    // scan blocks over cnt[0..N]

    char* ws = (char*)d_ws;
    size_t off = 0;
    auto alloc = [&](size_t bytes) { void* p = ws + off; off += (bytes + 255) & ~(size_t)255; return p; };
    unsigned short* q_ws  = (unsigned short*)alloc((size_t)N * 128 * 2);   // 12.8 MB
    unsigned short* k_ws  = (unsigned short*)alloc((size_t)N * 128 * 2);   // 12.8 MB
    uint2*          csr   = (uint2*)alloc((size_t)E * 8);                  // 6.4 MB
    float*          exb   = (float*)alloc((size_t)E * 2 * sizeof(float));  // 6.4 MB
    unsigned*       cnt   = (unsigned*)alloc((size_t)(N + 1) * 4);
    unsigned*       cursor= (unsigned*)alloc((size_t)N * 4);
    unsigned*       rsl   = (unsigned*)alloc((size_t)(N + 1) * 4);
    unsigned*       bsum  = (unsigned*)alloc((size_t)NB * 4);
    unsigned*       bpre  = (unsigned*)alloc((size_t)256 * 4);
    (void)ws_size;

    // zero cnt[0..N] and cursor[0..N-1] (adjacent allocations -> one memset)
    size_t zbytes = (size_t)((char*)(cursor + N) - (char*)cnt);
    hipMemsetAsync(cnt, 0, zbytes, stream);

    gemm_qk_mfma<<<(N + 127) / 128, 256, 0, stream>>>(x, W, b, q_ws, k_ws, N);
    hist_k<<<(E + 255) / 256, 256, 0, stream>>>(ei, cnt, E);
    scan_a<<<NB, 256, 0, stream>>>(cnt, rsl, bsum, N + 1);
    scan_b<<<1, 256, 0, stream>>>(bsum, bpre, NB);
    scat_k<<<(E + 255) / 256, 256, 0, stream>>>(ei, rsl, bpre, cursor, csr, E);
    row_k<<<((size_t)N * 16 + 255) / 256, 256, 0, stream>>>(q_ws, k_ws, csr, rsl, bpre, exb, out, N);
}